// Round 2
// baseline (306.889 us; speedup 1.0000x reference)
//
#include <hip/hip_runtime.h>

typedef __bf16 bf16x8 __attribute__((ext_vector_type(8)));
typedef float f32x4 __attribute__((ext_vector_type(4)));
typedef unsigned short u16;
typedef u16 u16x8 __attribute__((ext_vector_type(8)));
typedef u16 u16x2 __attribute__((ext_vector_type(2)));

__device__ __forceinline__ u16 f2bf(float f) {
    union { float f; unsigned u; } x; x.f = f;
    unsigned r = x.u + 0x7fffu + ((x.u >> 16) & 1u);
    return (u16)(r >> 16);
}
__device__ __forceinline__ bf16x8 as_bf16x8(u16x8 v) {
    return __builtin_bit_cast(bf16x8, v);
}

// C[m][n] = sum_k A[m][k] * B[n][k]   (A: MxK fp32, B: NxK fp32, C: MxN fp32)
// 64x64 tile, 4 waves (2x2 of 32x32), BK=32, bf16 MFMA 16x16x32.
__global__ __launch_bounds__(256) void gemm_bt(const float* __restrict__ A,
                                               const float* __restrict__ B,
                                               float* __restrict__ C,
                                               int M, int N, int K) {
    __shared__ u16 As[64][40];   // pad to 40 u16 = 80B stride (16B-aligned rows, 2-way bank alias = free)
    __shared__ u16 Bs[64][40];
    const int tid  = threadIdx.x;
    const int lane = tid & 63;
    const int wave = tid >> 6;
    const int m0 = blockIdx.y << 6;
    const int n0 = blockIdx.x << 6;
    const int wr = (wave >> 1) << 5;
    const int wc = (wave & 1) << 5;
    const int fr = lane & 15;
    const int fo = (lane >> 4) << 3;
    const int ar = tid >> 2;          // staging row 0..63
    const int ac = (tid & 3) << 3;    // staging col 0,8,16,24
    const float* Ap = A + (size_t)(m0 + ar) * K + ac;
    const float* Bp = B + (size_t)(n0 + ar) * K + ac;
    f32x4 acc[2][2] = {};
    for (int k0 = 0; k0 < K; k0 += 32) {
        float4 av0 = *(const float4*)(Ap + k0);
        float4 av1 = *(const float4*)(Ap + k0 + 4);
        float4 bv0 = *(const float4*)(Bp + k0);
        float4 bv1 = *(const float4*)(Bp + k0 + 4);
        __syncthreads();  // previous iteration's LDS reads done
        u16x8 ap, bp;
        ap[0] = f2bf(av0.x); ap[1] = f2bf(av0.y); ap[2] = f2bf(av0.z); ap[3] = f2bf(av0.w);
        ap[4] = f2bf(av1.x); ap[5] = f2bf(av1.y); ap[6] = f2bf(av1.z); ap[7] = f2bf(av1.w);
        bp[0] = f2bf(bv0.x); bp[1] = f2bf(bv0.y); bp[2] = f2bf(bv0.z); bp[3] = f2bf(bv0.w);
        bp[4] = f2bf(bv1.x); bp[5] = f2bf(bv1.y); bp[6] = f2bf(bv1.z); bp[7] = f2bf(bv1.w);
        *(u16x8*)&As[ar][ac] = ap;
        *(u16x8*)&Bs[ar][ac] = bp;
        __syncthreads();
        bf16x8 af0 = *(const bf16x8*)&As[wr + fr][fo];
        bf16x8 af1 = *(const bf16x8*)&As[wr + 16 + fr][fo];
        bf16x8 bf0 = *(const bf16x8*)&Bs[wc + fr][fo];
        bf16x8 bf1 = *(const bf16x8*)&Bs[wc + 16 + fr][fo];
        acc[0][0] = __builtin_amdgcn_mfma_f32_16x16x32_bf16(af0, bf0, acc[0][0], 0, 0, 0);
        acc[0][1] = __builtin_amdgcn_mfma_f32_16x16x32_bf16(af0, bf1, acc[0][1], 0, 0, 0);
        acc[1][0] = __builtin_amdgcn_mfma_f32_16x16x32_bf16(af1, bf0, acc[1][0], 0, 0, 0);
        acc[1][1] = __builtin_amdgcn_mfma_f32_16x16x32_bf16(af1, bf1, acc[1][1], 0, 0, 0);
    }
    const int cr = (lane >> 4) << 2;
    const int cc = lane & 15;
    for (int i = 0; i < 2; ++i)
        for (int j = 0; j < 2; ++j)
            for (int r = 0; r < 4; ++r)
                C[(size_t)(m0 + wr + i * 16 + cr + r) * N + (n0 + wc + j * 16 + cc)] = acc[i][j][r];
}

// qkv fp32 [B*S][3072] -> RoPE'd Q,K + V as bf16 in [b,h,s,64]
// grid MUST cover B*S*H*32 = 2^21 threads (8192 blocks of 256).
__global__ __launch_bounds__(256) void rope_split(const float* __restrict__ qkv,
                                                  const int* __restrict__ pos,
                                                  u16* __restrict__ Qb,
                                                  u16* __restrict__ Kb,
                                                  u16* __restrict__ Vb) {
    int tid = blockIdx.x * 256 + threadIdx.x;   // 0 .. 2^21-1
    int t = tid & 31;
    int h = (tid >> 5) & 15;
    int s = (tid >> 9) & 2047;
    int b = tid >> 20;                          // 0 or 1
    const float* row = qkv + (size_t)((b << 11) + s) * 3072;
    float fp  = (float)pos[s];
    float inv = powf(10000.0f, -(float)(2 * t) * (1.0f / 64.0f));
    float angle = fp * inv;
    float sn, cs;
    sincosf(angle, &sn, &cs);
    int off = h * 64 + 2 * t;
    float2 q2 = *(const float2*)(row + off);
    float2 k2 = *(const float2*)(row + 1024 + off);
    float2 v2 = *(const float2*)(row + 2048 + off);
    size_t oidx = (((size_t)(b * 16 + h) * 2048) + s) * 64 + 2 * t;
    u16x2 qo, ko, vo;
    qo[0] = f2bf(q2.x * cs - q2.y * sn);
    qo[1] = f2bf(q2.x * sn + q2.y * cs);
    ko[0] = f2bf(k2.x * cs - k2.y * sn);
    ko[1] = f2bf(k2.x * sn + k2.y * cs);
    vo[0] = f2bf(v2.x);
    vo[1] = f2bf(v2.y);
    *(u16x2*)&Qb[oidx] = qo;
    *(u16x2*)&Kb[oidx] = ko;
    *(u16x2*)&Vb[oidx] = vo;
}

// Flash attention, causal. 1 wave per (b, h, 16 q-rows). KBLK=32.
// Q,K,V bf16 [b,h,s,64]; O fp32 [b,s,h*64+d].
__global__ __launch_bounds__(64) void attn_causal(const u16* __restrict__ Q,
                                                  const u16* __restrict__ K,
                                                  const u16* __restrict__ V,
                                                  float* __restrict__ O) {
    const int lane = threadIdx.x;
    const int qt = blockIdx.x;
    const int h  = blockIdx.y;
    const int b  = blockIdx.z;
    const int S = 2048, H = 16;
    const size_t base = (size_t)(b * H + h) * S * 64;
    const int fr = lane & 15;
    const int fo = (lane >> 4) << 3;
    const int cr = (lane >> 4) << 2;
    __shared__ u16 Ps[16][32];
    bf16x8 aq[2];
    {
        const u16* qrow = Q + base + (size_t)(qt * 16 + fr) * 64;
        aq[0] = as_bf16x8(*(const u16x8*)(qrow + fo));
        aq[1] = as_bf16x8(*(const u16x8*)(qrow + 32 + fo));
    }
    float m[4], l[4];
    f32x4 oacc[4] = {};
    for (int j = 0; j < 4; ++j) { m[j] = -1e30f; l[j] = 0.0f; }
    const int ktmax = (qt * 16 + 15) >> 5;
    for (int kt = 0; kt <= ktmax; ++kt) {
        f32x4 sacc[2] = {};
        for (int ch = 0; ch < 2; ++ch) {
            const u16* krow = K + base + (size_t)(kt * 32 + ch * 16 + fr) * 64;
            bf16x8 bk0 = as_bf16x8(*(const u16x8*)(krow + fo));
            bf16x8 bk1 = as_bf16x8(*(const u16x8*)(krow + 32 + fo));
            sacc[ch] = __builtin_amdgcn_mfma_f32_16x16x32_bf16(aq[0], bk0, sacc[ch], 0, 0, 0);
            sacc[ch] = __builtin_amdgcn_mfma_f32_16x16x32_bf16(aq[1], bk1, sacc[ch], 0, 0, 0);
        }
        float p[2][4], alpha[4];
        for (int j = 0; j < 4; ++j) {
            int qp = qt * 16 + cr + j;
            float s0 = (kt * 32 + fr      <= qp) ? sacc[0][j] * 0.125f : -1e30f;
            float s1 = (kt * 32 + 16 + fr <= qp) ? sacc[1][j] * 0.125f : -1e30f;
            float rm = fmaxf(s0, s1);
            rm = fmaxf(rm, __shfl_xor(rm, 1));
            rm = fmaxf(rm, __shfl_xor(rm, 2));
            rm = fmaxf(rm, __shfl_xor(rm, 4));
            rm = fmaxf(rm, __shfl_xor(rm, 8));
            float newm = fmaxf(m[j], rm);
            alpha[j] = __expf(m[j] - newm);
            float e0 = __expf(s0 - newm);
            float e1 = __expf(s1 - newm);
            p[0][j] = e0; p[1][j] = e1;
            float r = e0 + e1;
            r += __shfl_xor(r, 1);
            r += __shfl_xor(r, 2);
            r += __shfl_xor(r, 4);
            r += __shfl_xor(r, 8);
            l[j] = l[j] * alpha[j] + r;
            m[j] = newm;
        }
        for (int t = 0; t < 4; ++t)
            for (int j = 0; j < 4; ++j)
                oacc[t][j] *= alpha[j];
        __syncthreads();  // previous iteration's Ps reads done
        for (int j = 0; j < 4; ++j) {
            Ps[cr + j][fr]      = f2bf(p[0][j]);
            Ps[cr + j][16 + fr] = f2bf(p[1][j]);
        }
        __syncthreads();
        bf16x8 pa = as_bf16x8(*(const u16x8*)&Ps[fr][fo]);
        for (int t = 0; t < 4; ++t) {
            u16x8 vv;
            const u16* vcol = V + base + (size_t)(kt * 32 + fo) * 64 + t * 16 + fr;
            #pragma unroll
            for (int jj = 0; jj < 8; ++jj) vv[jj] = vcol[(size_t)jj * 64];
            oacc[t] = __builtin_amdgcn_mfma_f32_16x16x32_bf16(pa, as_bf16x8(vv), oacc[t], 0, 0, 0);
        }
    }
    float inv_l[4];
    for (int j = 0; j < 4; ++j) inv_l[j] = 1.0f / l[j];
    for (int t = 0; t < 4; ++t)
        for (int j = 0; j < 4; ++j)
            O[((size_t)b * S + qt * 16 + cr + j) * 1024 + h * 64 + t * 16 + fr] =
                oacc[t][j] * inv_l[j];
}

extern "C" void kernel_launch(void* const* d_in, const int* in_sizes, int n_in,
                              void* d_out, int out_size, void* d_ws, size_t ws_size,
                              hipStream_t stream) {
    const float* x     = (const float*)d_in[0];   // [2,2048,1024]
    const float* qkv_w = (const float*)d_in[1];   // [3072,1024]
    const float* out_w = (const float*)d_in[2];   // [1024,1024]
    const int*   pos   = (const int*)d_in[3];     // [2048]
    float* out = (float*)d_out;                   // [2,2048,1024] fp32

    char* ws = (char*)d_ws;
    float* qkv = (float*)ws;                                   // 4096*3072*4 = 50331648 B
    u16*   Qb  = (u16*)(ws + 50331648);                        // 8388608 B each
    u16*   Kb  = (u16*)(ws + 50331648 + 8388608);
    u16*   Vb  = (u16*)(ws + 50331648 + 2 * 8388608);
    float* att = (float*)(ws + 50331648 + 3 * 8388608);        // 16777216 B

    // 1) qkv = x @ qkv_w^T : M=4096, N=3072, K=1024
    gemm_bt<<<dim3(48, 64), 256, 0, stream>>>(x, qkv_w, qkv, 4096, 3072, 1024);
    // 2) RoPE + split + bf16 convert to [b,h,s,64]  (2^21 threads = 8192 blocks)
    rope_split<<<8192, 256, 0, stream>>>(qkv, pos, Qb, Kb, Vb);
    // 3) causal flash attention -> att fp32 [b,s,1024]
    attn_causal<<<dim3(128, 16, 2), 64, 0, stream>>>(Qb, Kb, Vb, att);
    // 4) out = att @ out_w^T : M=4096, N=1024, K=1024
    gemm_bt<<<dim3(16, 64), 256, 0, stream>>>(att, out_w, out, 4096, 1024, 1024);
}

// Round 3
// 219.583 us; speedup vs baseline: 1.3976x; 1.3976x over previous
//
#include <hip/hip_runtime.h>

typedef __bf16 bf16x8 __attribute__((ext_vector_type(8)));
typedef float f32x4 __attribute__((ext_vector_type(4)));
typedef unsigned short u16;
typedef u16 u16x8 __attribute__((ext_vector_type(8)));
typedef u16 u16x2 __attribute__((ext_vector_type(2)));

__device__ __forceinline__ u16 f2bf(float f) {
    union { float f; unsigned u; } x; x.f = f;
    unsigned r = x.u + 0x7fffu + ((x.u >> 16) & 1u);
    return (u16)(r >> 16);
}
__device__ __forceinline__ bf16x8 as_bf16x8(u16x8 v) {
    return __builtin_bit_cast(bf16x8, v);
}
__device__ __forceinline__ void glds16(const void* g, void* l) {
    __builtin_amdgcn_global_load_lds(
        (const __attribute__((address_space(1))) void*)g,
        (__attribute__((address_space(3))) void*)l, 16, 0, 0);
}
// per-row XOR swizzle (u16 units, 8-aligned chunks): bijective, conflict-free b128 reads
__device__ __forceinline__ int swz(int r) { return (((r & 7) ^ ((r >> 3) & 7)) << 3); }

// fp32 -> bf16, 8 elems/thread
__global__ __launch_bounds__(256) void f32bf16(const float* __restrict__ in,
                                               u16* __restrict__ out, int n8) {
    int i = blockIdx.x * 256 + threadIdx.x;
    if (i >= n8) return;
    const float4* p = (const float4*)(in + (size_t)i * 8);
    float4 a = p[0], b = p[1];
    u16x8 o;
    o[0] = f2bf(a.x); o[1] = f2bf(a.y); o[2] = f2bf(a.z); o[3] = f2bf(a.w);
    o[4] = f2bf(b.x); o[5] = f2bf(b.y); o[6] = f2bf(b.z); o[7] = f2bf(b.w);
    *(u16x8*)(out + (size_t)i * 8) = o;
}

// C[m][n] = sum_k A[m][k]*B[n][k]; A,B bf16 row-major, C fp32.
// 128x128 tile, 4 waves (2x2 of 64x64), BK=32, global_load_lds + 2-phase dbuf.
__global__ __launch_bounds__(256) void gemm128(const u16* __restrict__ A,
                                               const u16* __restrict__ B,
                                               float* __restrict__ C,
                                               int M, int N, int K) {
    __shared__ u16 As[2][4096];   // [128][32] linear, matches gload_lds lane order
    __shared__ u16 Bs[2][4096];
    const int tid = threadIdx.x, lane = tid & 63, wave = tid >> 6;
    const int m0 = blockIdx.y << 7, n0 = blockIdx.x << 7;
    const int wr = (wave >> 1) << 6, wc = (wave & 1) << 6;
    const int fr = lane & 15, fo = (lane >> 4) << 3;
    const int srow = tid >> 2, scol = (tid & 3) << 3;
    const u16* Ag = A + (size_t)(m0 + srow) * K + scol;
    const u16* Bg = B + (size_t)(n0 + srow) * K + scol;
    u16* AsW = &As[0][0] + (wave << 9);   // wave-uniform LDS base (+lane*16B by HW)
    u16* BsW = &Bs[0][0] + (wave << 9);
    f32x4 acc[4][4] = {};
    const int nsteps = K >> 5;
    glds16(Ag, AsW);
    glds16(Ag + (size_t)64 * K, AsW + 2048);
    glds16(Bg, BsW);
    glds16(Bg + (size_t)64 * K, BsW + 2048);
    int cur = 0;
    for (int s = 0; s < nsteps; ++s) {
        __syncthreads();   // buf[cur] staged (drains vmcnt), prev reads done
        if (s + 1 < nsteps) {
            const u16* Ap = Ag + (s + 1) * 32;
            const u16* Bp = Bg + (s + 1) * 32;
            const int nb = (cur ^ 1) << 12;
            glds16(Ap, AsW + nb);
            glds16(Ap + (size_t)64 * K, AsW + nb + 2048);
            glds16(Bp, BsW + nb);
            glds16(Bp + (size_t)64 * K, BsW + nb + 2048);
        }
        const u16* Ab = &As[cur][0];
        const u16* Bb = &Bs[cur][0];
        bf16x8 af[4], bfr[4];
        #pragma unroll
        for (int i = 0; i < 4; ++i)
            af[i] = *(const bf16x8*)(Ab + (wr + i * 16 + fr) * 32 + fo);
        #pragma unroll
        for (int i = 0; i < 4; ++i)
            bfr[i] = *(const bf16x8*)(Bb + (wc + i * 16 + fr) * 32 + fo);
        #pragma unroll
        for (int i = 0; i < 4; ++i)
            #pragma unroll
            for (int j = 0; j < 4; ++j)
                acc[i][j] = __builtin_amdgcn_mfma_f32_16x16x32_bf16(af[i], bfr[j], acc[i][j], 0, 0, 0);
        cur ^= 1;
    }
    const int cr = (lane >> 4) << 2, cc = lane & 15;
    #pragma unroll
    for (int i = 0; i < 4; ++i)
        for (int j = 0; j < 4; ++j)
            for (int r = 0; r < 4; ++r)
                C[(size_t)(m0 + wr + i * 16 + cr + r) * N + (n0 + wc + j * 16 + cc)] = acc[i][j][r];
}

// qkv fp32 [B*S][3072] -> RoPE'd Q (pre-scaled by 1/8), K, V bf16 [b,h,s,64]
__global__ __launch_bounds__(256) void rope_split(const float* __restrict__ qkv,
                                                  const int* __restrict__ pos,
                                                  u16* __restrict__ Qb,
                                                  u16* __restrict__ Kb,
                                                  u16* __restrict__ Vb) {
    int tid = blockIdx.x * 256 + threadIdx.x;   // 0 .. 2^21-1
    int t = tid & 31;
    int h = (tid >> 5) & 15;
    int s = (tid >> 9) & 2047;
    int b = tid >> 20;
    const float* row = qkv + (size_t)((b << 11) + s) * 3072;
    float fp  = (float)pos[s];
    float inv = powf(10000.0f, -(float)(2 * t) * (1.0f / 64.0f));
    float angle = fp * inv;
    float sn, cs;
    sincosf(angle, &sn, &cs);
    int off = h * 64 + 2 * t;
    float2 q2 = *(const float2*)(row + off);
    float2 k2 = *(const float2*)(row + 1024 + off);
    float2 v2 = *(const float2*)(row + 2048 + off);
    size_t oidx = (((size_t)(b * 16 + h) * 2048) + s) * 64 + 2 * t;
    u16x2 qo, ko, vo;
    qo[0] = f2bf((q2.x * cs - q2.y * sn) * 0.125f);
    qo[1] = f2bf((q2.x * sn + q2.y * cs) * 0.125f);
    ko[0] = f2bf(k2.x * cs - k2.y * sn);
    ko[1] = f2bf(k2.x * sn + k2.y * cs);
    vo[0] = f2bf(v2.x);
    vo[1] = f2bf(v2.y);
    *(u16x2*)&Qb[oidx] = qo;
    *(u16x2*)&Kb[oidx] = ko;
    *(u16x2*)&Vb[oidx] = vo;
}

// Causal flash attention. Block = 4 waves, QBLK=64 (16 q-rows/wave), KBLK=64.
// K,V staged in swizzled LDS (V transposed at staging); P via per-wave LDS.
// Output bf16 [b*s][1024].
__global__ __launch_bounds__(256) void attn_causal(const u16* __restrict__ Q,
                                                   const u16* __restrict__ K,
                                                   const u16* __restrict__ V,
                                                   u16* __restrict__ O) {
    __shared__ u16 Ks[4096];       // [key][d] swizzled
    __shared__ u16 Vt[4096];       // [d][key] swizzled (transposed at staging)
    __shared__ u16 Ps[4][1024];    // per-wave [qrow][key] swizzled
    const int tid = threadIdx.x, lane = tid & 63, wave = tid >> 6;
    const int qt = blockIdx.x, h = blockIdx.y, b = blockIdx.z;
    const int S = 2048, H = 16;
    const size_t base = (size_t)(b * H + h) * S * 64;
    const int fr = lane & 15, fo = (lane >> 4) << 3, cr = (lane >> 4) << 2;
    const int qw = (qt << 6) + (wave << 4);
    bf16x8 aq[2];
    {
        const u16* qrow = Q + base + (size_t)(qw + fr) * 64;
        aq[0] = as_bf16x8(*(const u16x8*)(qrow + fo));
        aq[1] = as_bf16x8(*(const u16x8*)(qrow + 32 + fo));
    }
    float m[4], l[4];
    f32x4 oacc[4] = {};
    #pragma unroll
    for (int j = 0; j < 4; ++j) { m[j] = -1e30f; l[j] = 0.f; }
    const int srow = tid >> 3, scol = (tid & 7) << 3;
    const int nkt = qt + 1;
    u16x8 kreg[2], vreg[2];
    #pragma unroll
    for (int p = 0; p < 2; ++p) {
        kreg[p] = *(const u16x8*)(K + base + (size_t)(srow + p * 32) * 64 + scol);
        vreg[p] = *(const u16x8*)(V + base + (size_t)(srow + p * 32) * 64 + scol);
    }
    for (int kt = 0; kt < nkt; ++kt) {
        __syncthreads();   // prev tile's LDS reads complete
        #pragma unroll
        for (int p = 0; p < 2; ++p) {
            const int row = srow + p * 32;
            *(u16x8*)&Ks[row * 64 + (scol ^ swz(row))] = kreg[p];
            #pragma unroll
            for (int j = 0; j < 8; ++j) {
                const int d = scol + j;
                Vt[d * 64 + (row ^ swz(d))] = vreg[p][j];
            }
        }
        __syncthreads();   // staged
        if (kt + 1 < nkt) {   // async-stage split: issue next tile's loads now
            #pragma unroll
            for (int p = 0; p < 2; ++p) {
                const u16* kp = K + base + (size_t)((kt + 1) * 64 + srow + p * 32) * 64 + scol;
                const u16* vp = V + base + (size_t)((kt + 1) * 64 + srow + p * 32) * 64 + scol;
                kreg[p] = *(const u16x8*)kp;
                vreg[p] = *(const u16x8*)vp;
            }
        }
        const bool diag = (kt == qt);
        const int nch = diag ? wave + 1 : 4;
        f32x4 sacc[4];
        #pragma unroll
        for (int ch = 0; ch < 4; ++ch) {
            if (ch < nch) {
                const int r = ch * 16 + fr;
                const int sw = swz(r);
                bf16x8 bk0 = *(const bf16x8*)&Ks[r * 64 + (fo ^ sw)];
                bf16x8 bk1 = *(const bf16x8*)&Ks[r * 64 + ((32 + fo) ^ sw)];
                f32x4 sc = {};
                sc = __builtin_amdgcn_mfma_f32_16x16x32_bf16(aq[0], bk0, sc, 0, 0, 0);
                sc = __builtin_amdgcn_mfma_f32_16x16x32_bf16(aq[1], bk1, sc, 0, 0, 0);
                sacc[ch] = sc;
            }
        }
        float alpha[4];
        #pragma unroll
        for (int j = 0; j < 4; ++j) {
            float sv[4];
            float rm = -1e30f;
            #pragma unroll
            for (int ch = 0; ch < 4; ++ch) {
                float s = (ch < nch) ? sacc[ch][j] : -1e30f;
                if (diag && ch == wave && fr > cr + j) s = -1e30f;
                sv[ch] = s;
                rm = fmaxf(rm, s);
            }
            rm = fmaxf(rm, __shfl_xor(rm, 1));
            rm = fmaxf(rm, __shfl_xor(rm, 2));
            rm = fmaxf(rm, __shfl_xor(rm, 4));
            rm = fmaxf(rm, __shfl_xor(rm, 8));
            const float nm = fmaxf(m[j], rm);
            alpha[j] = __expf(m[j] - nm);
            const int prow = cr + j;
            const int swp = swz(prow);
            float rs = 0.f;
            #pragma unroll
            for (int ch = 0; ch < 4; ++ch) {
                float e = __expf(sv[ch] - nm);   // masked -> exp(-huge) = 0
                Ps[wave][prow * 64 + ((ch * 16 + fr) ^ swp)] = f2bf(e);
                rs += e;
            }
            rs += __shfl_xor(rs, 1);
            rs += __shfl_xor(rs, 2);
            rs += __shfl_xor(rs, 4);
            rs += __shfl_xor(rs, 8);
            l[j] = l[j] * alpha[j] + rs;
            m[j] = nm;
        }
        #pragma unroll
        for (int t = 0; t < 4; ++t)
            #pragma unroll
            for (int j = 0; j < 4; ++j)
                oacc[t][j] *= alpha[j];
        const int npv = diag ? ((wave + 2) >> 1) : 2;
        const int swf = swz(fr);
        #pragma unroll
        for (int kk = 0; kk < 2; ++kk) {
            if (kk < npv) {
                bf16x8 pa = *(const bf16x8*)&Ps[wave][fr * 64 + ((kk * 32 + fo) ^ swf)];
                #pragma unroll
                for (int t = 0; t < 4; ++t) {
                    const int d = t * 16 + fr;
                    bf16x8 bv = *(const bf16x8*)&Vt[d * 64 + ((kk * 32 + fo) ^ swz(d))];
                    oacc[t] = __builtin_amdgcn_mfma_f32_16x16x32_bf16(pa, bv, oacc[t], 0, 0, 0);
                }
            }
        }
    }
    #pragma unroll
    for (int j = 0; j < 4; ++j) l[j] = 1.f / l[j];
    #pragma unroll
    for (int t = 0; t < 4; ++t)
        for (int j = 0; j < 4; ++j)
            O[(size_t)(b * S + qw + cr + j) * 1024 + h * 64 + t * 16 + fr] =
                f2bf(oacc[t][j] * l[j]);
}

extern "C" void kernel_launch(void* const* d_in, const int* in_sizes, int n_in,
                              void* d_out, int out_size, void* d_ws, size_t ws_size,
                              hipStream_t stream) {
    const float* x     = (const float*)d_in[0];   // [2,2048,1024]
    const float* qkv_w = (const float*)d_in[1];   // [3072,1024]
    const float* out_w = (const float*)d_in[2];   // [1024,1024]
    const int*   pos   = (const int*)d_in[3];     // [2048]
    float* out = (float*)d_out;                   // [2,2048,1024] fp32

    char* ws = (char*)d_ws;
    float* qkv  = (float*)ws;                        // 50331648 B
    u16*   Qb   = (u16*)(ws + 50331648);             // 8388608 B
    u16*   Kb   = (u16*)(ws + 58720256);             // 8388608 B
    u16*   Vb   = (u16*)(ws + 67108864);             // 8388608 B
    u16*   x16  = (u16*)(ws + 75497472);             // 8388608 B (reused as att16)
    u16*   att16= (u16*)(ws + 75497472);
    u16*   w16  = (u16*)(ws + 83886080);             // 6291456 B
    u16*   ow16 = (u16*)(ws + 90177536);             // 2097152 B  (total 92274688)

    // 0) fp32 -> bf16 converts
    f32bf16<<<2048, 256, 0, stream>>>(x, x16, 524288);
    f32bf16<<<1536, 256, 0, stream>>>(qkv_w, w16, 393216);
    f32bf16<<<512, 256, 0, stream>>>(out_w, ow16, 131072);
    // 1) qkv = x @ qkv_w^T : M=4096, N=3072, K=1024
    gemm128<<<dim3(24, 32), 256, 0, stream>>>(x16, w16, qkv, 4096, 3072, 1024);
    // 2) RoPE + split (Q pre-scaled by 1/8)
    rope_split<<<8192, 256, 0, stream>>>(qkv, pos, Qb, Kb, Vb);
    // 3) causal flash attention -> att16 bf16 [4096][1024]
    attn_causal<<<dim3(32, 16, 2), 256, 0, stream>>>(Qb, Kb, Vb, att16);
    // 4) out = att16 @ out_w^T : M=4096, N=1024, K=1024
    gemm128<<<dim3(8, 32), 256, 0, stream>>>(att16, ow16, out, 4096, 1024, 1024);
}

// Round 5
// 142.749 us; speedup vs baseline: 2.1498x; 1.5382x over previous
//
#include <hip/hip_runtime.h>

typedef __bf16 bf16x8 __attribute__((ext_vector_type(8)));
typedef float f32x4 __attribute__((ext_vector_type(4)));
typedef unsigned short u16;
typedef u16 u16x8 __attribute__((ext_vector_type(8)));
typedef u16 u16x4 __attribute__((ext_vector_type(4)));
typedef u16 u16x2 __attribute__((ext_vector_type(2)));

__device__ __forceinline__ u16 f2bf(float f) {
    union { float f; unsigned u; } x; x.f = f;
    unsigned r = x.u + 0x7fffu + ((x.u >> 16) & 1u);
    return (u16)(r >> 16);
}
__device__ __forceinline__ bf16x8 as_bf16x8(u16x8 v) {
    return __builtin_bit_cast(bf16x8, v);
}
__device__ __forceinline__ void glds16(const void* g, void* l) {
    __builtin_amdgcn_global_load_lds(
        (const __attribute__((address_space(1))) void*)g,
        (__attribute__((address_space(3))) void*)l, 16, 0, 0);
}
// per-row XOR swizzle (u16 units, 8-aligned chunks): bijective, low-conflict b128/b64 access
__device__ __forceinline__ int swz(int r) { return (((r & 7) ^ ((r >> 3) & 7)) << 3); }

// fp32 -> bf16, 8 elems/thread
__global__ __launch_bounds__(256) void f32bf16(const float* __restrict__ in,
                                               u16* __restrict__ out, int n8) {
    int i = blockIdx.x * 256 + threadIdx.x;
    if (i >= n8) return;
    const float4* p = (const float4*)(in + (size_t)i * 8);
    float4 a = p[0], b = p[1];
    u16x8 o;
    o[0] = f2bf(a.x); o[1] = f2bf(a.y); o[2] = f2bf(a.z); o[3] = f2bf(a.w);
    o[4] = f2bf(b.x); o[5] = f2bf(b.y); o[6] = f2bf(b.z); o[7] = f2bf(b.w);
    *(u16x8*)(out + (size_t)i * 8) = o;
}

// C[m][n] = sum_k A[m][k]*B[n][k]; A,B bf16 row-major, C fp32.
// 128x128 tile, 4 waves (2x2 of 64x64), BK=32, global_load_lds + 2-phase dbuf.
__global__ __launch_bounds__(256) void gemm128(const u16* __restrict__ A,
                                               const u16* __restrict__ B,
                                               float* __restrict__ C,
                                               int M, int N, int K) {
    __shared__ u16 As[2][4096];   // [128][32] linear, matches gload_lds lane order
    __shared__ u16 Bs[2][4096];
    const int tid = threadIdx.x, lane = tid & 63, wave = tid >> 6;
    const int m0 = blockIdx.y << 7, n0 = blockIdx.x << 7;
    const int wr = (wave >> 1) << 6, wc = (wave & 1) << 6;
    const int fr = lane & 15, fo = (lane >> 4) << 3;
    const int srow = tid >> 2, scol = (tid & 3) << 3;
    const u16* Ag = A + (size_t)(m0 + srow) * K + scol;
    const u16* Bg = B + (size_t)(n0 + srow) * K + scol;
    u16* AsW = &As[0][0] + (wave << 9);   // wave-uniform LDS base (+lane*16B by HW)
    u16* BsW = &Bs[0][0] + (wave << 9);
    f32x4 acc[4][4] = {};
    const int nsteps = K >> 5;
    glds16(Ag, AsW);
    glds16(Ag + (size_t)64 * K, AsW + 2048);
    glds16(Bg, BsW);
    glds16(Bg + (size_t)64 * K, BsW + 2048);
    int cur = 0;
    for (int s = 0; s < nsteps; ++s) {
        __syncthreads();   // buf[cur] staged (drains vmcnt), prev reads done
        if (s + 1 < nsteps) {
            const u16* Ap = Ag + (s + 1) * 32;
            const u16* Bp = Bg + (s + 1) * 32;
            const int nb = (cur ^ 1) << 12;
            glds16(Ap, AsW + nb);
            glds16(Ap + (size_t)64 * K, AsW + nb + 2048);
            glds16(Bp, BsW + nb);
            glds16(Bp + (size_t)64 * K, BsW + nb + 2048);
        }
        const u16* Ab = &As[cur][0];
        const u16* Bb = &Bs[cur][0];
        bf16x8 af[4], bfr[4];
        #pragma unroll
        for (int i = 0; i < 4; ++i)
            af[i] = *(const bf16x8*)(Ab + (wr + i * 16 + fr) * 32 + fo);
        #pragma unroll
        for (int i = 0; i < 4; ++i)
            bfr[i] = *(const bf16x8*)(Bb + (wc + i * 16 + fr) * 32 + fo);
        #pragma unroll
        for (int i = 0; i < 4; ++i)
            #pragma unroll
            for (int j = 0; j < 4; ++j)
                acc[i][j] = __builtin_amdgcn_mfma_f32_16x16x32_bf16(af[i], bfr[j], acc[i][j], 0, 0, 0);
        cur ^= 1;
    }
    const int cr = (lane >> 4) << 2, cc = lane & 15;
    #pragma unroll
    for (int i = 0; i < 4; ++i)
        for (int j = 0; j < 4; ++j)
            for (int r = 0; r < 4; ++r)
                C[(size_t)(m0 + wr + i * 16 + cr + r) * N + (n0 + wc + j * 16 + cc)] = acc[i][j][r];
}

// qkv fp32 [B*S][3072] -> RoPE'd Q (pre-scaled by 0.125*log2(e)), K, V bf16 [b,h,s,64]
__global__ __launch_bounds__(256) void rope_split(const float* __restrict__ qkv,
                                                  const int* __restrict__ pos,
                                                  u16* __restrict__ Qb,
                                                  u16* __restrict__ Kb,
                                                  u16* __restrict__ Vb) {
    int tid = blockIdx.x * 256 + threadIdx.x;   // 0 .. 2^21-1
    int t = tid & 31;
    int h = (tid >> 5) & 15;
    int s = (tid >> 9) & 2047;
    int b = tid >> 20;
    const float* row = qkv + (size_t)((b << 11) + s) * 3072;
    float fp  = (float)pos[s];
    float inv = powf(10000.0f, -(float)(2 * t) * (1.0f / 64.0f));
    float angle = fp * inv;
    float sn, cs;
    sincosf(angle, &sn, &cs);
    int off = h * 64 + 2 * t;
    float2 q2 = *(const float2*)(row + off);
    float2 k2 = *(const float2*)(row + 1024 + off);
    float2 v2 = *(const float2*)(row + 2048 + off);
    size_t oidx = (((size_t)(b * 16 + h) * 2048) + s) * 64 + 2 * t;
    const float qs = 0.18033688011112042f;   // 0.125 * log2(e): exp(x) = exp2(x*log2e)
    u16x2 qo, ko, vo;
    qo[0] = f2bf((q2.x * cs - q2.y * sn) * qs);
    qo[1] = f2bf((q2.x * sn + q2.y * cs) * qs);
    ko[0] = f2bf(k2.x * cs - k2.y * sn);
    ko[1] = f2bf(k2.x * sn + k2.y * cs);
    vo[0] = f2bf(v2.x);
    vo[1] = f2bf(v2.y);
    *(u16x2*)&Qb[oidx] = qo;
    *(u16x2*)&Kb[oidx] = ko;
    *(u16x2*)&Vb[oidx] = vo;
}

// Causal flash attention, NO online max (scores bounded: |s| <= |q||k|/8 << 88).
// Block = 4 waves, each wave 16 q-rows (QBLK=64), KBLK=64, LDS double-buffered.
// Each block processes q-tile pair (qt, 31-qt): constant 33 K-tiles -> perfect balance.
// P stored k-interleaved (pos = (k&15)*4 + (k>>4)) so each lane's 4 exp results are
// one ds_write_b64; V LDS columns use the same permutation (consistent => valid).
// NOTE: because of the interleave, QK^T chunk ch maps to packed positions
// pos == ch (mod 4), spread over BOTH kk-halves -> PV must always run both kk
// (masked chunks wrote P=0, so full PV is exact). Skipping kk here was the R4 bug.
// l = sum_k P via ones-MFMA. Output bf16 [b*s][1024].
__global__ __launch_bounds__(256) void attn_causal(const u16* __restrict__ Q,
                                                   const u16* __restrict__ K,
                                                   const u16* __restrict__ V,
                                                   u16* __restrict__ O) {
    __shared__ u16 Ks[2][4096];    // [key][d] swizzled, dbuf
    __shared__ u16 Vt[2][4096];    // [d][kpos] swizzled (transposed at staging), dbuf
    __shared__ u16 Ps[4][1024];    // per-wave [qrow][kpos] swizzled
    const int tid = threadIdx.x, lane = tid & 63, wave = tid >> 6;
    const int pr = blockIdx.x, h = blockIdx.y, b = blockIdx.z;
    const int S = 2048, H = 16;
    const size_t base = (size_t)(b * H + h) * S * 64;
    const int fr = lane & 15, fo = (lane >> 4) << 3, cr = (lane >> 4) << 2;
    const int srow = tid >> 3, scol = (tid & 7) << 3;
    u16x8 ones_u;
    #pragma unroll
    for (int i = 0; i < 8; ++i) ones_u[i] = 0x3F80;   // bf16 1.0
    const bf16x8 ones = as_bf16x8(ones_u);

    u16x8 kreg[2], vreg[2];
    #pragma unroll
    for (int phase = 0; phase < 2; ++phase) {
        const int qt = phase ? (31 - pr) : pr;
        const int nkt = qt + 1;
        const int qw = (qt << 6) + (wave << 4);
        bf16x8 aq0, aq1;
        {
            const u16* qrow = Q + base + (size_t)(qw + fr) * 64;
            aq0 = as_bf16x8(*(const u16x8*)(qrow + fo));
            aq1 = as_bf16x8(*(const u16x8*)(qrow + 32 + fo));
        }
        f32x4 oacc[4] = {};
        f32x4 lacc = {};
        // load K/V tile 0 into regs
        #pragma unroll
        for (int p = 0; p < 2; ++p) {
            kreg[p] = *(const u16x8*)(K + base + (size_t)(srow + p * 32) * 64 + scol);
            vreg[p] = *(const u16x8*)(V + base + (size_t)(srow + p * 32) * 64 + scol);
        }
        __syncthreads();   // previous phase's LDS readers done
        // stage tile 0 into buf 0
        #pragma unroll
        for (int p = 0; p < 2; ++p) {
            const int row = srow + (p << 5);
            *(u16x8*)&Ks[0][row * 64 + (scol ^ swz(row))] = kreg[p];
            const int pos = ((row & 15) << 2) + (row >> 4);
            #pragma unroll
            for (int j = 0; j < 8; ++j) {
                const int d = scol + j;
                Vt[0][d * 64 + (pos ^ swz(d))] = vreg[p][j];
            }
        }
        if (nkt > 1) {
            #pragma unroll
            for (int p = 0; p < 2; ++p) {
                kreg[p] = *(const u16x8*)(K + base + (size_t)(64 + srow + p * 32) * 64 + scol);
                vreg[p] = *(const u16x8*)(V + base + (size_t)(64 + srow + p * 32) * 64 + scol);
            }
        }
        for (int t = 0; t < nkt; ++t) {
            __syncthreads();   // buf[t&1] staged by all; readers of buf[(t+1)&1] done
            if (t + 1 < nkt) {
                const int bi = (t + 1) & 1;
                #pragma unroll
                for (int p = 0; p < 2; ++p) {
                    const int row = srow + (p << 5);
                    *(u16x8*)&Ks[bi][row * 64 + (scol ^ swz(row))] = kreg[p];
                    const int pos = ((row & 15) << 2) + (row >> 4);
                    #pragma unroll
                    for (int j = 0; j < 8; ++j) {
                        const int d = scol + j;
                        Vt[bi][d * 64 + (pos ^ swz(d))] = vreg[p][j];
                    }
                }
                if (t + 2 < nkt) {
                    #pragma unroll
                    for (int p = 0; p < 2; ++p) {
                        const u16* kp = K + base + (size_t)(((t + 2) << 6) + srow + p * 32) * 64 + scol;
                        const u16* vp = V + base + (size_t)(((t + 2) << 6) + srow + p * 32) * 64 + scol;
                        kreg[p] = *(const u16x8*)kp;
                        vreg[p] = *(const u16x8*)vp;
                    }
                }
            }
            const u16* Kb = &Ks[t & 1][0];
            const u16* Vb = &Vt[t & 1][0];
            const bool diag = (t == nkt - 1);
            const int nch = diag ? wave + 1 : 4;
            // QK^T (chunks of 16 keys)
            f32x4 sacc[4];
            #pragma unroll
            for (int ch = 0; ch < 4; ++ch) {
                if (ch < nch) {
                    const int r = ch * 16 + fr;
                    const int sw = swz(r);
                    bf16x8 bk0 = *(const bf16x8*)&Kb[r * 64 + (fo ^ sw)];
                    bf16x8 bk1 = *(const bf16x8*)&Kb[r * 64 + ((32 + fo) ^ sw)];
                    f32x4 sc = {};
                    sc = __builtin_amdgcn_mfma_f32_16x16x32_bf16(aq0, bk0, sc, 0, 0, 0);
                    sc = __builtin_amdgcn_mfma_f32_16x16x32_bf16(aq1, bk1, sc, 0, 0, 0);
                    sacc[ch] = sc;
                }
            }
            // exp (scores pre-scaled to log2 domain) + packed b64 P write
            #pragma unroll
            for (int j = 0; j < 4; ++j) {
                const int prow = cr + j;
                u16x4 pk;
                #pragma unroll
                for (int ch = 0; ch < 4; ++ch) {
                    float e = 0.f;
                    if (ch < nch) {
                        if (!(diag && ch == wave && fr > prow)) e = exp2f(sacc[ch][j]);
                    }
                    pk[ch] = f2bf(e);
                }
                *(u16x4*)&Ps[wave][prow * 64 + ((fr << 2) ^ swz(prow))] = pk;
            }
            // PV + row-sum (ones-MFMA). ALWAYS both kk halves: packed interleave
            // spreads every chunk across both halves; masked entries are 0.
            #pragma unroll
            for (int kk = 0; kk < 2; ++kk) {
                const int pbase = (kk << 5) + fo;
                bf16x8 pa = *(const bf16x8*)&Ps[wave][fr * 64 + (pbase ^ swz(fr))];
                lacc = __builtin_amdgcn_mfma_f32_16x16x32_bf16(pa, ones, lacc, 0, 0, 0);
                #pragma unroll
                for (int tt = 0; tt < 4; ++tt) {
                    const int d = tt * 16 + fr;
                    bf16x8 bv = *(const bf16x8*)&Vb[d * 64 + (pbase ^ swz(d))];
                    oacc[tt] = __builtin_amdgcn_mfma_f32_16x16x32_bf16(pa, bv, oacc[tt], 0, 0, 0);
                }
            }
        }
        // epilogue: normalize and store bf16
        f32x4 inv;
        #pragma unroll
        for (int j = 0; j < 4; ++j) inv[j] = 1.f / lacc[j];
        #pragma unroll
        for (int tt = 0; tt < 4; ++tt)
            for (int j = 0; j < 4; ++j)
                O[(size_t)(b * S + qw + cr + j) * 1024 + h * 64 + tt * 16 + fr] =
                    f2bf(oacc[tt][j] * inv[j]);
    }
}

extern "C" void kernel_launch(void* const* d_in, const int* in_sizes, int n_in,
                              void* d_out, int out_size, void* d_ws, size_t ws_size,
                              hipStream_t stream) {
    const float* x     = (const float*)d_in[0];   // [2,2048,1024]
    const float* qkv_w = (const float*)d_in[1];   // [3072,1024]
    const float* out_w = (const float*)d_in[2];   // [1024,1024]
    const int*   pos   = (const int*)d_in[3];     // [2048]
    float* out = (float*)d_out;                   // [2,2048,1024] fp32

    char* ws = (char*)d_ws;
    float* qkv  = (float*)ws;                        // 50331648 B
    u16*   Qb   = (u16*)(ws + 50331648);             // 8388608 B
    u16*   Kb   = (u16*)(ws + 58720256);             // 8388608 B
    u16*   Vb   = (u16*)(ws + 67108864);             // 8388608 B
    u16*   x16  = (u16*)(ws + 75497472);             // 8388608 B (reused as att16)
    u16*   att16= (u16*)(ws + 75497472);
    u16*   w16  = (u16*)(ws + 83886080);             // 6291456 B
    u16*   ow16 = (u16*)(ws + 90177536);             // 2097152 B  (total 92274688)

    // 0) fp32 -> bf16 converts
    f32bf16<<<2048, 256, 0, stream>>>(x, x16, 524288);
    f32bf16<<<1536, 256, 0, stream>>>(qkv_w, w16, 393216);
    f32bf16<<<512, 256, 0, stream>>>(out_w, ow16, 131072);
    // 1) qkv = x @ qkv_w^T : M=4096, N=3072, K=1024
    gemm128<<<dim3(24, 32), 256, 0, stream>>>(x16, w16, qkv, 4096, 3072, 1024);
    // 2) RoPE + split (Q pre-scaled by 0.125*log2e)
    rope_split<<<8192, 256, 0, stream>>>(qkv, pos, Qb, Kb, Vb);
    // 3) causal flash attention -> att16 bf16 [4096][1024]; blocks do pair (qt, 31-qt)
    attn_causal<<<dim3(16, 16, 2), 256, 0, stream>>>(Qb, Kb, Vb, att16);
    // 4) out = att16 @ out_w^T : M=4096, N=1024, K=1024
    gemm128<<<dim3(8, 32), 256, 0, stream>>>(att16, ow16, out, 4096, 1024, 1024);
}